// Round 10
// baseline (1052.903 us; speedup 1.0000x reference)
//
#include <hip/hip_runtime.h>

using half8   = __attribute__((ext_vector_type(8))) _Float16;
using floatx4 = __attribute__((ext_vector_type(4))) float;

namespace {
constexpr int S = 196, D = 512, C = 1006, Cpad = 1024;
constexpr int CB = 16;      // block c-tile
constexpr int EBLK = 256;   // block e-tile (x2 tanh duplication - reg-wall forced)
constexpr int BK = 64;      // k-chunk (8 chunks, 2 MFMA k-steps each)
constexpr int TPB = 256;    // 4 waves
constexpr int SPP = 2;      // s per pass: acc = 32 AGPR
constexpr int SCH = 4;      // s-chunks of 49 -> grid 1024 = 4 blocks/CU
constexpr int RS = 64;      // LDS row stride (halfs); banks via XOR swizzle
constexpr float KTANH = 2.885390082f;    // 2/ln2 folded into img staging
constexpr float INVK  = 0.34657359028f;  // ln2/2 to recover raw img
constexpr float LOG2E = 1.44269504f;     // folded into W at prep

// ws layout (bytes) — NEED = 34,078,720 B (r2/r6 ran the slice path at this size)
constexpr size_t W16_BYTES = (size_t)D * D * 2;               // 512 KB swizzled W
constexpr size_t LA_OFF    = W16_BYTES;
constexpr size_t SLICE_ELEMS = (size_t)2 * Cpad * D;
constexpr size_t SL_BYTES  = (size_t)SCH * SLICE_ELEMS * 4;   // 16 MB per set
constexpr size_t SLICE_NEED = LA_OFF + 2 * SL_BYTES;
constexpr size_t L_BYTES   = SLICE_ELEMS * 4;

// swizzled LDS offset (halfs): row stride 64, 16B-seg XOR'd by row&7
// (conflict-free on b128 frag reads — SQ_LDS_BANK_CONFLICT==0 since r3)
__device__ __forceinline__ int sw_off(int row, int seg) {
    return row * RS + ((seg ^ (row & 7)) << 3);
}

__device__ __forceinline__ void gload16(const _Float16* g, _Float16* l) {
    // async global->LDS, 16B/lane; LDS dest = wave-uniform base + lane*16
    __builtin_amdgcn_global_load_lds(
        (const __attribute__((address_space(1))) unsigned int*)g,
        (__attribute__((address_space(3))) unsigned int*)l, 16, 0, 0);
}

__device__ __forceinline__ _Float16 tanh_ps(float y) {
    // y = (2/ln2)*x; tanh(x) = 1 - 2/(exp2(y)+1); saturates correctly
    float e = __builtin_amdgcn_exp2f(y);
    return (_Float16)(1.0f - 2.0f * __builtin_amdgcn_rcpf(e + 1.0f));
}

// Pre-swizzle fc3_w*log2e into the exact per-chunk LDS image
// (8 chunks of 512 rows x 8 16B-segs, seg XOR row&7) — same image the kernel DMAs.
__global__ void prep_w16sw(const float* __restrict__ fw, _Float16* __restrict__ W16sw) {
    int id = blockIdx.x * blockDim.x + threadIdx.x;    // 32768 segs
    int kki = id >> 12;
    int r   = (id >> 3) & 511;
    int j   = id & 7;
    const float* src = fw + (size_t)r * D + kki * BK + j * 8;
    floatx4 v0 = *(const floatx4*)src;
    floatx4 v1 = *(const floatx4*)(src + 4);
    half8 h;
    h[0] = (_Float16)(v0[0] * LOG2E); h[1] = (_Float16)(v0[1] * LOG2E);
    h[2] = (_Float16)(v0[2] * LOG2E); h[3] = (_Float16)(v0[3] * LOG2E);
    h[4] = (_Float16)(v1[0] * LOG2E); h[5] = (_Float16)(v1[1] * LOG2E);
    h[6] = (_Float16)(v1[2] * LOG2E); h[7] = (_Float16)(v1[3] * LOG2E);
    *(half8*)&W16sw[((size_t)kki << 15) + r * RS + ((j ^ (r & 7)) << 3)] = h;
}

// NO launch_bounds reg-cap games beyond waves hint: r9 proved cap<demand => spill
// catastrophe. Demand here is ~116-122 unified (sums 32 + working ~55 + acc 32 AGPR)
// which fits 4 waves/SIMD (<=128) organically.
__global__ __launch_bounds__(TPB, 4) void semdec_mfma(
    const float* __restrict__ img, const float* __restrict__ word,
    const _Float16* __restrict__ W16sw,
    float* __restrict__ lbase, float* __restrict__ abase, int use_slice)
{
    __shared__ __align__(16) _Float16 Wc[EBLK * RS];     // 32768 B
    __shared__ __align__(16) _Float16 Tc[SPP * CB * RS]; // 4096 B (2s x 16c x 64k)
    __shared__ __align__(16) float imgS[SPP][D];         // 4096 B, pre-scaled 2/ln2
    // total 40960 B exactly -> 4 blocks/CU (160 KB exact fit)

    const int ct = blockIdx.x;           // 0..63
    const int et = blockIdx.y & 1;       // 0..1
    const int b  = blockIdx.y >> 1;      // 0..1
    const int sc = blockIdx.z;           // 0..3

    const int tid  = threadIdx.x;
    const int lane = tid & 63;
    const int wv   = tid >> 6;           // wave 0..3 = 64-wide e-slot
    const int l15  = lane & 15;
    const int quad = lane >> 4;

    const int c0 = ct * CB;
    const int e0 = et * EBLK;

    // T-stage mapping: 2s x 16c x 8 segs = 256 half8 -> one per thread
    const int siT  = tid >> 7;           // 0..1
    const int ciT  = (tid & 127) >> 3;   // 0..15
    const int segT = tid & 7;            // 0..7
    int cgT = c0 + ciT; if (cgT > C - 1) cgT = C - 1;   // clamp pad rows
    const float* wordRowT = word + (size_t)cgT * D + segT * 8;

    floatx4 lacc[4], aacc[4];            // 32 VGPR softmax sums
    #pragma unroll
    for (int ej = 0; ej < 4; ++ej) {
        lacc[ej] = (floatx4){0.f, 0.f, 0.f, 0.f};
        aacc[ej] = (floatx4){0.f, 0.f, 0.f, 0.f};
    }

    const float* imgB = img + (size_t)b * S * D;
    const int s_base = sc * 49;          // 49 = 24 pairs + 1 single

    for (int pr = 0; pr < 25; ++pr) {
        const int s0 = s_base + pr * 2;
        const int slim = (pr == 24) ? 1 : 2;   // last pass covers 1 s

        __syncthreads();  // prior pass readers of imgS/Tc/Wc done
        {   // stage 2 pre-scaled img rows: 256 float4 -> one per thread
            int si = tid >> 7, pos = (tid & 127) << 2;
            int srow = s0 + si; if (srow > S - 1) srow = S - 1;   // tail clamp
            floatx4 v = *(const floatx4*)&imgB[(size_t)srow * D + pos];
            floatx4 sv = {v[0] * KTANH, v[1] * KTANH, v[2] * KTANH, v[3] * KTANH};
            *(floatx4*)&imgS[si][pos] = sv;
        }

        floatx4 acc[SPP][4];   // [si][ej] 32 AGPR
        #pragma unroll
        for (int si = 0; si < SPP; ++si)
            #pragma unroll
            for (int ej = 0; ej < 4; ++ej)
                acc[si][ej] = (floatx4){0.f, 0.f, 0.f, 0.f};

        for (int kk = 0; kk < D; kk += BK) {
            const int kki = kk >> 6;
            __syncthreads();  // prev chunk frag readers done / imgS staged (kk=0)
            // --- word load for this chunk issued first (L2 ~200cyc, covered by
            //     the DMA-issue + ds_read instructions below + 16-wave/CU TLP)
            const float* wp = wordRowT + kk;
            floatx4 w0 = *(const floatx4*)wp;
            floatx4 w1 = *(const floatx4*)(wp + 4);
            // --- W chunk: async DMA of pre-swizzled image, 8 x 1KB per wave
            {
                const _Float16* wg = W16sw + ((size_t)kki << 15) + ((size_t)e0 << 6);
                #pragma unroll
                for (int it = 0; it < 8; ++it) {
                    int o = ((wv * 8 + it) << 9) + (lane << 3);
                    gload16(wg + o, &Wc[o]);
                }
            }
            // --- T chunk: one half8 per thread
            {
                const float* ip = &imgS[siT][kk + segT * 8];
                floatx4 i0 = *(const floatx4*)ip;
                floatx4 i1 = *(const floatx4*)(ip + 4);
                half8 t;
                t[0] = tanh_ps(i0[0] * w0[0]); t[1] = tanh_ps(i0[1] * w0[1]);
                t[2] = tanh_ps(i0[2] * w0[2]); t[3] = tanh_ps(i0[3] * w0[3]);
                t[4] = tanh_ps(i1[0] * w1[0]); t[5] = tanh_ps(i1[1] * w1[1]);
                t[6] = tanh_ps(i1[2] * w1[2]); t[7] = tanh_ps(i1[3] * w1[3]);
                *(half8*)&Tc[sw_off(siT * CB + ciT, segT)] = t;
            }
            __syncthreads();  // drains vmcnt (async W) + lgkm (T writes)

            // --- MFMA: 2 k-steps of 32; bf loaded per-ej (lean reg window)
            #pragma unroll
            for (int k2 = 0; k2 < 2; ++k2) {
                const int jb = (k2 << 2) + quad;
                half8 af[SPP];
                #pragma unroll
                for (int si = 0; si < SPP; ++si)
                    af[si] = *(const half8*)&Tc[sw_off(si * CB + l15, jb)];
                #pragma unroll
                for (int ej = 0; ej < 4; ++ej) {
                    half8 bf = *(const half8*)&Wc[sw_off(wv * 64 + ej * 16 + l15, jb)];
                    #pragma unroll
                    for (int si = 0; si < SPP; ++si)
                        acc[si][ej] = __builtin_amdgcn_mfma_f32_16x16x32_f16(
                            af[si], bf, acc[si][ej], 0, 0, 0);
                }
            }
        }
        // --- online softmax accumulate; acc = log2e*feat so exp2(acc) = exp(feat)
        #pragma unroll
        for (int si = 0; si < SPP; ++si) {
            if (si >= slim) break;
            #pragma unroll
            for (int ej = 0; ej < 4; ++ej) {
                float ie = imgS[si][e0 + wv * 64 + ej * 16 + l15] * INVK;
                #pragma unroll
                for (int r = 0; r < 4; ++r) {
                    float ev = __builtin_amdgcn_exp2f(acc[si][ej][r]);
                    lacc[ej][r] += ev;
                    aacc[ej][r] += ie * ev;
                }
            }
        }
    }

    // --- writeout (C/D layout: col=lane&15 -> e, row=quad*4+r -> c)
    if (use_slice) {
        float* lsl = lbase + (size_t)sc * SLICE_ELEMS;
        float* asl = abase + (size_t)sc * SLICE_ELEMS;
        #pragma unroll
        for (int r = 0; r < 4; ++r) {
            int cg = c0 + quad * 4 + r;
            #pragma unroll
            for (int ej = 0; ej < 4; ++ej) {
                int eg = e0 + wv * 64 + ej * 16 + l15;
                size_t o = ((size_t)b * Cpad + cg) * D + eg;
                lsl[o] = lacc[ej][r];
                asl[o] = aacc[ej][r];
            }
        }
    } else {
        #pragma unroll
        for (int r = 0; r < 4; ++r) {
            int cg = c0 + quad * 4 + r;
            #pragma unroll
            for (int ej = 0; ej < 4; ++ej) {
                int eg = e0 + wv * 64 + ej * 16 + l15;
                atomicAdd(&lbase[((size_t)b * Cpad + cg) * D + eg], lacc[ej][r]);
                if (cg < C)
                    atomicAdd(&abase[((size_t)b * C + cg) * D + eg], aacc[ej][r]);
            }
        }
    }
}

__global__ void finalize_k(const float* __restrict__ lbase, const float* __restrict__ abase,
                           float* __restrict__ out, int use_slice) {
    int o = blockIdx.x * blockDim.x + threadIdx.x;
    if (o >= 2 * C * D) return;
    int b = o / (C * D);
    int rem = o - b * (C * D);
    int c = rem >> 9;
    int e = rem & (D - 1);
    size_t p = ((size_t)b * Cpad + c) * D + e;
    if (use_slice) {
        float l = 0.f, a = 0.f;
        #pragma unroll
        for (int scn = 0; scn < SCH; ++scn) {
            l += lbase[(size_t)scn * SLICE_ELEMS + p];
            a += abase[(size_t)scn * SLICE_ELEMS + p];
        }
        out[o] = a / l;
    } else {
        out[o] = out[o] / lbase[p];
    }
}

} // namespace

extern "C" void kernel_launch(void* const* d_in, const int* in_sizes, int n_in,
                              void* d_out, int out_size, void* d_ws, size_t ws_size,
                              hipStream_t stream) {
    const float* img  = (const float*)d_in[0];
    const float* word = (const float*)d_in[1];
    const float* fw   = (const float*)d_in[2];
    // d_in[3] = fc3_b: constant over softmax axis s -> cancels exactly.
    float* out = (float*)d_out;
    char* ws = (char*)d_ws;

    _Float16* W16sw = (_Float16*)ws;
    const int use_slice = (ws_size >= SLICE_NEED) ? 1 : 0;

    hipLaunchKernelGGL(prep_w16sw, dim3(128), dim3(256), 0, stream, fw, W16sw);

    float *lbase, *abase;
    if (use_slice) {
        lbase = (float*)(ws + LA_OFF);
        abase = (float*)(ws + LA_OFF + SL_BYTES);
    } else {
        lbase = (float*)(ws + LA_OFF);
        abase = out;
        hipMemsetAsync(lbase, 0, L_BYTES, stream);
        hipMemsetAsync(out, 0, (size_t)2 * C * D * 4, stream);
    }

    hipLaunchKernelGGL(semdec_mfma, dim3(64, 4, SCH), dim3(TPB), 0, stream,
                       img, word, W16sw, lbase, abase, use_slice);

    hipLaunchKernelGGL(finalize_k, dim3((2 * C * D + 255) / 256), dim3(256), 0, stream,
                       lbase, abase, out, use_slice);
}

// Round 11
// 603.515 us; speedup vs baseline: 1.7446x; 1.7446x over previous
//
#include <hip/hip_runtime.h>

using half8   = __attribute__((ext_vector_type(8))) _Float16;
using half2v  = __attribute__((ext_vector_type(2))) _Float16;
using floatx2 = __attribute__((ext_vector_type(2))) float;
using floatx4 = __attribute__((ext_vector_type(4))) float;

namespace {
constexpr int S = 196, D = 512, C = 1006, Cpad = 1024;
constexpr int CB = 16;      // block c-tile
constexpr int BK = 32;      // k-chunk (16 chunks, 1 MFMA k-step each)
constexpr int NCH = 16;
constexpr int TPB = 1024;   // 16 waves, 1 block/CU, mandatory 4 waves/SIMD
constexpr int SPP = 4;      // s per pass
constexpr int SCH = 2;      // s-chunks of 98 -> grid 256 = 1 block/CU
constexpr int SUMR = 513;   // sums row length in (l,a)-pairs (odd -> bank spread)
constexpr float KTANH = 2.885390082f;    // 2/ln2 folded into img staging
constexpr float INVK  = 0.34657359028f;  // ln2/2 to recover raw img
constexpr float LOG2E = 1.44269504f;     // folded into W at prep

// ws layout (bytes) — NEED ≈ 17.3 MB (< 24.5 MB slice path proven in r4/r8)
constexpr size_t W16_BYTES = (size_t)D * D * 2;               // 512 KB swizzled W
constexpr size_t LA_OFF    = W16_BYTES;
constexpr size_t SLICE_ELEMS = (size_t)2 * Cpad * D;          // 4 MB slice
constexpr size_t SL_BYTES  = (size_t)SCH * SLICE_ELEMS * 4;   // 8 MB per set
constexpr size_t SLICE_NEED = LA_OFF + 2 * SL_BYTES;
constexpr size_t L_BYTES   = SLICE_ELEMS * 4;

// BK=32 chunk-local swizzle: slot(row in 0..511, seg in 0..3) -> 16B unit.
// Rows 0..7 at fixed seg hit 8 distinct 16B columns (uniform floor-rate for
// b128 frag reads); rows 8.. repeat 2-way (free).
__device__ __forceinline__ int slotWT(int row, int seg) {
    return row * 4 + (seg ^ ((row >> 1) & 3));
}

__device__ __forceinline__ void gload16(const _Float16* g, _Float16* l) {
    // async global->LDS, 16B/lane; LDS dest = wave-uniform base + lane*16
    __builtin_amdgcn_global_load_lds(
        (const __attribute__((address_space(1))) unsigned int*)g,
        (__attribute__((address_space(3))) unsigned int*)l, 16, 0, 0);
}

__device__ __forceinline__ _Float16 tanh_ps(float y) {
    // y = (2/ln2)*x; tanh(x) = 1 - 2/(exp2(y)+1); saturates correctly
    float e = __builtin_amdgcn_exp2f(y);
    return (_Float16)(1.0f - 2.0f * __builtin_amdgcn_rcpf(e + 1.0f));
}

// Pre-swizzle fc3_w*log2e into the exact per-chunk LDS image:
// 16 chunks (kki) x 512 rows x 4 segs of 8 halfs, slotWT layout.
__global__ void prep_w16sw(const float* __restrict__ fw, _Float16* __restrict__ W16sw) {
    int id = blockIdx.x * blockDim.x + threadIdx.x;    // 32768 segs
    int kki = id >> 11;
    int rem = id & 2047;
    int r   = rem >> 2;
    int j   = rem & 3;
    const float* src = fw + (size_t)r * D + kki * BK + j * 8;
    floatx4 v0 = *(const floatx4*)src;
    floatx4 v1 = *(const floatx4*)(src + 4);
    half8 h;
    h[0] = (_Float16)(v0[0] * LOG2E); h[1] = (_Float16)(v0[1] * LOG2E);
    h[2] = (_Float16)(v0[2] * LOG2E); h[3] = (_Float16)(v0[3] * LOG2E);
    h[4] = (_Float16)(v1[0] * LOG2E); h[5] = (_Float16)(v1[1] * LOG2E);
    h[6] = (_Float16)(v1[2] * LOG2E); h[7] = (_Float16)(v1[3] * LOG2E);
    *(half8*)&W16sw[((size_t)kki << 14) + (slotWT(r, j) << 3)] = h;
}

__global__ __launch_bounds__(TPB) void semdec_mfma(
    const float* __restrict__ img, const float* __restrict__ word,
    const _Float16* __restrict__ W16sw,
    float* __restrict__ lbase, float* __restrict__ abase, int use_slice)
{
    __shared__ __align__(16) _Float16 Wc[D * BK];        // 32 KB (512 e x 32 k)
    __shared__ __align__(16) _Float16 Tc[SPP * CB * BK]; // 4 KB
    __shared__ __align__(16) float imgS[SPP][D];         // 8 KB (pre-scaled 2/ln2)
    __shared__ __align__(16) float sums[CB * SUMR * 2];  // 65664 B (l,a pairs)
    // total ~110 KB -> 1 block/CU; softmax sums live in LDS, NOT registers:
    // per-thread state = acc(32) only -> fits the mandatory 128-reg cap.

    const int ct = blockIdx.x;           // 0..63
    const int b  = blockIdx.y;           // 0..1
    const int sc = blockIdx.z;           // 0..1

    const int tid  = threadIdx.x;
    const int lane = tid & 63;
    const int wv   = tid >> 6;           // wave 0..15 = 32-wide e-slot
    const int l15  = lane & 15;
    const int quad = lane >> 4;

    const int c0 = ct * CB;

    // T-stage mapping: 4s x 16c x 32k = 2048 halfs -> 2 per thread (half2)
    const int rowT = tid >> 4;           // 0..63 = siT*16 + clT
    const int siT  = rowT >> 4;
    const int clT  = rowT & 15;
    const int kpT  = tid & 15;           // k pair index
    const int kT   = kpT * 2;
    const int segT = kpT >> 2;
    const int tcA  = (slotWT(rowT, segT) << 3) + (kT & 7);   // halfs
    int cgT = c0 + clT; if (cgT > C - 1) cgT = C - 1;        // clamp pad rows
    const float* wordPtr = word + (size_t)cgT * D + kT;

    // zero-init LDS sums (8 pairs per thread)
    #pragma unroll
    for (int i = 0; i < 8; ++i) {
        int id = i * TPB + tid;          // 8192 pairs
        int c = id >> 9, e = id & 511;
        *(floatx2*)&sums[(c * SUMR + e) * 2] = (floatx2){0.f, 0.f};
    }

    const float* imgB = img + (size_t)b * S * D;
    const int s_base = sc * 98;          // 98 = 24*4 + 2

    floatx2 wcur = *(const floatx2*)wordPtr;   // chunk-0 word pair (cyclic k)

    for (int pr = 0; pr < 25; ++pr) {
        const int s0 = s_base + pr * SPP;
        const int slim = (pr == 24) ? 2 : 4;

        __syncthreads();  // prev pass: accum imgS readers + last MFMA done
        if (tid < 512) {  // stage 4 pre-scaled img rows
            int si = tid >> 7, pos = (tid & 127) << 2;
            int srow = s0 + si; if (srow > S - 1) srow = S - 1;   // tail clamp
            floatx4 v = *(const floatx4*)&imgB[(size_t)srow * D + pos];
            floatx4 sv = {v[0] * KTANH, v[1] * KTANH, v[2] * KTANH, v[3] * KTANH};
            *(floatx4*)&imgS[si][pos] = sv;
        }

        floatx4 acc[SPP][2];   // [si][ej] = 32 regs, the ONLY persistent state
        #pragma unroll
        for (int si = 0; si < SPP; ++si)
            #pragma unroll
            for (int ej = 0; ej < 2; ++ej)
                acc[si][ej] = (floatx4){0.f, 0.f, 0.f, 0.f};

        for (int kki = 0; kki < NCH; ++kki) {
            const int kk = kki * BK;
            __syncthreads();  // prev chunk frag readers done / imgS visible (kki=0)
            // --- W chunk: async DMA, 2 KB per wave (32 KB total)
            {
                const _Float16* wg = W16sw + ((size_t)kki << 14);
                #pragma unroll
                for (int it = 0; it < 2; ++it) {
                    int o = ((wv * 2 + it) << 9) + (lane << 3);
                    gload16(wg + o, &Wc[o]);
                }
            }
            // --- T chunk: 2 tanh per thread (word pair prefetched last chunk)
            {
                floatx2 iv = *(const floatx2*)&imgS[siT][kk + kT];
                half2v t;
                t[0] = tanh_ps(iv[0] * wcur[0]);
                t[1] = tanh_ps(iv[1] * wcur[1]);
                *(half2v*)&Tc[tcA] = t;
            }
            // prefetch next chunk's word pair (cyclic); lands during the
            // barrier2 drain alongside the DMA (parallel, not serial)
            {
                const int kn = (kk + BK) & (D - 1);
                wcur = *(const floatx2*)(wordPtr + kn);
            }
            __syncthreads();  // drains vmcnt (DMA + word) + lgkm (T writes)

            // --- MFMA: 1 k-step of 32; af[4] + 2x bf -> 8 MFMA
            half8 af[SPP];
            #pragma unroll
            for (int si = 0; si < SPP; ++si)
                af[si] = *(const half8*)&Tc[slotWT(si * CB + l15, quad) << 3];
            #pragma unroll
            for (int ej = 0; ej < 2; ++ej) {
                half8 bf = *(const half8*)&Wc[slotWT(wv * 32 + ej * 16 + l15, quad) << 3];
                #pragma unroll
                for (int si = 0; si < SPP; ++si)
                    acc[si][ej] = __builtin_amdgcn_mfma_f32_16x16x32_f16(
                        af[si], bf, acc[si][ej], 0, 0, 0);
            }
        }

        // --- online softmax accumulate into LDS sums (each (c,e) owned by
        //     exactly one thread -> plain read-modify-write, no atomics)
        #pragma unroll
        for (int ej = 0; ej < 2; ++ej) {
            const int e = wv * 32 + ej * 16 + l15;
            float ie[SPP];
            #pragma unroll
            for (int si = 0; si < SPP; ++si)
                ie[si] = imgS[si][e] * INVK;
            #pragma unroll
            for (int r = 0; r < 4; ++r) {
                const int c = quad * 4 + r;
                float* p = &sums[(c * SUMR + e) * 2];
                floatx2 la = *(floatx2*)p;
                #pragma unroll
                for (int si = 0; si < SPP; ++si) {
                    if (si >= slim) break;
                    float ev = __builtin_amdgcn_exp2f(acc[si][ej][r]);
                    la[0] += ev;
                    la[1] += ie[si] * ev;
                }
                *(floatx2*)p = la;
            }
        }
    }

    // --- writeout: each thread stores its 8 owned (c,e) pairs
    if (use_slice) {
        float* lsl = lbase + (size_t)sc * SLICE_ELEMS;
        float* asl = abase + (size_t)sc * SLICE_ELEMS;
        #pragma unroll
        for (int ej = 0; ej < 2; ++ej) {
            const int e = wv * 32 + ej * 16 + l15;
            #pragma unroll
            for (int r = 0; r < 4; ++r) {
                const int c = quad * 4 + r;
                floatx2 la = *(floatx2*)&sums[(c * SUMR + e) * 2];
                size_t o = ((size_t)b * Cpad + c0 + c) * D + e;
                lsl[o] = la[0];
                asl[o] = la[1];
            }
        }
    } else {
        #pragma unroll
        for (int ej = 0; ej < 2; ++ej) {
            const int e = wv * 32 + ej * 16 + l15;
            #pragma unroll
            for (int r = 0; r < 4; ++r) {
                const int c = quad * 4 + r;
                floatx2 la = *(floatx2*)&sums[(c * SUMR + e) * 2];
                int cg = c0 + c;
                atomicAdd(&lbase[((size_t)b * Cpad + cg) * D + e], la[0]);
                if (cg < C)
                    atomicAdd(&abase[((size_t)b * C + cg) * D + e], la[1]);
            }
        }
    }
}

__global__ void finalize_k(const float* __restrict__ lbase, const float* __restrict__ abase,
                           float* __restrict__ out, int use_slice) {
    int o = blockIdx.x * blockDim.x + threadIdx.x;
    if (o >= 2 * C * D) return;
    int b = o / (C * D);
    int rem = o - b * (C * D);
    int c = rem >> 9;
    int e = rem & (D - 1);
    size_t p = ((size_t)b * Cpad + c) * D + e;
    if (use_slice) {
        float l = 0.f, a = 0.f;
        #pragma unroll
        for (int scn = 0; scn < SCH; ++scn) {
            l += lbase[(size_t)scn * SLICE_ELEMS + p];
            a += abase[(size_t)scn * SLICE_ELEMS + p];
        }
        out[o] = a / l;
    } else {
        out[o] = out[o] / lbase[p];
    }
}

} // namespace

extern "C" void kernel_launch(void* const* d_in, const int* in_sizes, int n_in,
                              void* d_out, int out_size, void* d_ws, size_t ws_size,
                              hipStream_t stream) {
    const float* img  = (const float*)d_in[0];
    const float* word = (const float*)d_in[1];
    const float* fw   = (const float*)d_in[2];
    // d_in[3] = fc3_b: constant over softmax axis s -> cancels exactly.
    float* out = (float*)d_out;
    char* ws = (char*)d_ws;

    _Float16* W16sw = (_Float16*)ws;
    const int use_slice = (ws_size >= SLICE_NEED) ? 1 : 0;

    hipLaunchKernelGGL(prep_w16sw, dim3(128), dim3(256), 0, stream, fw, W16sw);

    float *lbase, *abase;
    if (use_slice) {
        lbase = (float*)(ws + LA_OFF);
        abase = (float*)(ws + LA_OFF + SL_BYTES);
    } else {
        lbase = (float*)(ws + LA_OFF);
        abase = out;
        hipMemsetAsync(lbase, 0, L_BYTES, stream);
        hipMemsetAsync(out, 0, (size_t)2 * C * D * 4, stream);
    }

    hipLaunchKernelGGL(semdec_mfma, dim3(64, 2, SCH), dim3(TPB), 0, stream,
                       img, word, W16sw, lbase, abase, use_slice);

    hipLaunchKernelGGL(finalize_k, dim3((2 * C * D + 255) / 256), dim3(256), 0, stream,
                       lbase, abase, out, use_slice);
}

// Round 13
// 361.145 us; speedup vs baseline: 2.9155x; 1.6711x over previous
//
#include <hip/hip_runtime.h>

using half8   = __attribute__((ext_vector_type(8))) _Float16;
using half2v  = __attribute__((ext_vector_type(2))) _Float16;
using fp16x2  = __attribute__((ext_vector_type(2))) __fp16;
using floatx4 = __attribute__((ext_vector_type(4))) float;

namespace {
constexpr int S = 196, D = 512, C = 1006, Cpad = 1024;
constexpr int CB = 16;      // block c-tile
constexpr int EBLK = 256;   // block e-tile (x2 tanh duplication - reg-wall forced)
constexpr int BK = 64;      // k-chunk (8 chunks, 2 MFMA k-steps each)
constexpr int TPB = 256;    // 4 waves; 3 blocks/CU (reg-limited: ~84 VGPR + 64 AGPR)
constexpr int SCH = 3;      // s-chunks 66/66/64 -> grid 768 = 3 blocks/CU
constexpr int RS = 64;      // LDS row stride (halfs); banks via XOR swizzle
constexpr float KTANH = 2.885390082f;    // 2/ln2 folded into img staging
constexpr float INVK  = 0.34657359028f;  // ln2/2 to recover raw img
constexpr float LOG2E = 1.44269504f;     // folded into W at prep

// ws layout (bytes)
constexpr size_t W16_BYTES = (size_t)D * D * 2;               // 512 KB swizzled W
constexpr size_t LA_OFF    = W16_BYTES;
constexpr size_t SLICE_ELEMS = (size_t)2 * Cpad * D;
constexpr size_t SL_BYTES  = (size_t)SCH * SLICE_ELEMS * 4;   // 12 MB per set
constexpr size_t SLICE_NEED = LA_OFF + 2 * SL_BYTES;          // ~24.5 MB (proven fits)
constexpr size_t L_BYTES   = SLICE_ELEMS * 4;

// swizzled LDS offset (halfs): row stride 64, 16B-seg XOR'd by row&7
// (conflict-free on b128 frag reads — SQ_LDS_BANK_CONFLICT==0 since r3)
__device__ __forceinline__ int sw_off(int row, int seg) {
    return row * RS + ((seg ^ (row & 7)) << 3);
}

__device__ __forceinline__ void gload16(const _Float16* g, _Float16* l) {
    // async global->LDS, 16B/lane; LDS dest = wave-uniform base + lane*16
    __builtin_amdgcn_global_load_lds(
        (const __attribute__((address_space(1))) unsigned int*)g,
        (__attribute__((address_space(3))) unsigned int*)l, 16, 0, 0);
}

__device__ __forceinline__ float tanh_f(float y) {
    // y = (2/ln2)*x; tanh(x) = 1 - 2/(exp2(y)+1); saturates correctly
    float e = __builtin_amdgcn_exp2f(y);
    return 1.0f - 2.0f * __builtin_amdgcn_rcpf(e + 1.0f);
}

__device__ __forceinline__ half2v pk2(float a, float b) {
    // v_cvt_pkrtz_f16_f32: 2 f32->f16 converts in one instr; bitcast elem type
    fp16x2 r = __builtin_amdgcn_cvt_pkrtz(a, b);
    return __builtin_bit_cast(half2v, r);
}

// Pre-swizzle fc3_w*log2e into the exact per-chunk LDS image
// (8 chunks of 512 rows x 8 16B-segs, seg XOR row&7) — same image the kernel DMAs.
__global__ void prep_w16sw(const float* __restrict__ fw, _Float16* __restrict__ W16sw) {
    int id = blockIdx.x * blockDim.x + threadIdx.x;    // 32768 segs
    int kki = id >> 12;
    int r   = (id >> 3) & 511;
    int j   = id & 7;
    const float* src = fw + (size_t)r * D + kki * BK + j * 8;
    floatx4 v0 = *(const floatx4*)src;
    floatx4 v1 = *(const floatx4*)(src + 4);
    half8 h;
    h[0] = (_Float16)(v0[0] * LOG2E); h[1] = (_Float16)(v0[1] * LOG2E);
    h[2] = (_Float16)(v0[2] * LOG2E); h[3] = (_Float16)(v0[3] * LOG2E);
    h[4] = (_Float16)(v1[0] * LOG2E); h[5] = (_Float16)(v1[1] * LOG2E);
    h[6] = (_Float16)(v1[2] * LOG2E); h[7] = (_Float16)(v1[3] * LOG2E);
    *(half8*)&W16sw[((size_t)kki << 15) + r * RS + ((j ^ (r & 7)) << 3)] = h;
}

__global__ __launch_bounds__(TPB, 3) void semdec_mfma(
    const float* __restrict__ img, const float* __restrict__ word,
    const _Float16* __restrict__ W16sw,
    float* __restrict__ lbase, float* __restrict__ abase, int use_slice)
{
    __shared__ __align__(16) _Float16 Wc[EBLK * RS];   // 32 KB
    __shared__ __align__(16) _Float16 Tc[4 * CB * RS]; // 8 KB (4 s x 16 c x 64 k)
    __shared__ __align__(16) float imgS[4][D];         // 8 KB, pre-scaled by 2/ln2
    // total 48 KB -> 3 blocks/CU

    const int ct = blockIdx.x;           // 0..63
    const int et = blockIdx.y & 1;       // 0..1
    const int b  = blockIdx.y >> 1;      // 0..1
    const int sc = blockIdx.z;           // 0..2

    const int tid  = threadIdx.x;
    const int lane = tid & 63;
    const int wv   = tid >> 6;           // wave 0..3 = 64-wide e-slot
    const int l15  = lane & 15;
    const int quad = lane >> 4;

    const int c0 = ct * CB;
    const int e0 = et * EBLK;

    // T-stage mapping: thread -> fixed (ciT, segT); si = it*2 + siB
    const int siB  = tid >> 7;           // 0..1
    const int ciT  = (tid & 127) >> 3;   // 0..15
    const int segT = tid & 7;            // 0..7
    int cgT = c0 + ciT; if (cgT > C - 1) cgT = C - 1;   // clamp pad rows
    const float* wordRowT = word + (size_t)cgT * D + segT * 8;

    floatx4 lacc[4], aacc[4];            // 32 VGPR softmax sums
    #pragma unroll
    for (int ej = 0; ej < 4; ++ej) {
        lacc[ej] = (floatx4){0.f, 0.f, 0.f, 0.f};
        aacc[ej] = (floatx4){0.f, 0.f, 0.f, 0.f};
    }

    const float* imgB = img + (size_t)b * S * D;
    const int s_base = sc * 66;                       // 0, 66, 132
    const int npass = (sc < 2) ? 17 : 16;             // 16x4s (+1x2s for sc<2)

    // word values for chunk 0 (addresses depend only on kk -> cyclic prefetch)
    floatx4 wc0 = *(const floatx4*)(wordRowT);
    floatx4 wc1 = *(const floatx4*)(wordRowT + 4);

    for (int pr = 0; pr < npass; ++pr) {
        const int s0 = s_base + pr * 4;
        const bool full = (pr != 16);                 // tail pass covers only 2 s
        const int slim = full ? 4 : 2;

        __syncthreads();  // prior pass readers of imgS/Tc/Wc done
        #pragma unroll
        for (int it = 0; it < 2; ++it) {
            int sid = it * TPB + tid;
            int si = sid >> 7, pos = (sid & 127) << 2;
            floatx4 v = *(const floatx4*)&imgB[(size_t)(s0 + si) * D + pos];
            floatx4 sv = {v[0] * KTANH, v[1] * KTANH, v[2] * KTANH, v[3] * KTANH};
            *(floatx4*)&imgS[si][pos] = sv;
        }

        floatx4 acc[4][4];   // [si][ej] 64 AGPR
        #pragma unroll
        for (int si = 0; si < 4; ++si)
            #pragma unroll
            for (int ej = 0; ej < 4; ++ej)
                acc[si][ej] = (floatx4){0.f, 0.f, 0.f, 0.f};

        for (int kk = 0; kk < D; kk += BK) {
            const int kki = kk >> 6;
            __syncthreads();  // prev chunk frag readers done / imgS staged (kk=0)
            // --- W chunk: async DMA of pre-swizzled image, 8 x 1KB per wave
            {
                const _Float16* wg = W16sw + ((size_t)kki << 15) + ((size_t)e0 << 6);
                #pragma unroll
                for (int it = 0; it < 8; ++it) {
                    int o = ((wv * 8 + it) << 9) + (lane << 3);
                    gload16(wg + o, &Wc[o]);
                }
            }
            // --- T chunk: 4s x 16c x 8 segs, one half8 per thread per it;
            //     pack via cvt_pkrtz (2 f32->f16 per instr); word vals prefetched
            #pragma unroll
            for (int it = 0; it < 2; ++it) {
                if (it == 1 && !full) break;          // tail: skip si=2,3 tanh
                int si = it * 2 + siB;
                const float* ip = &imgS[si][kk + segT * 8];
                floatx4 i0 = *(const floatx4*)ip;
                floatx4 i1 = *(const floatx4*)(ip + 4);
                half2v p0 = pk2(tanh_f(i0[0] * wc0[0]), tanh_f(i0[1] * wc0[1]));
                half2v p1 = pk2(tanh_f(i0[2] * wc0[2]), tanh_f(i0[3] * wc0[3]));
                half2v p2 = pk2(tanh_f(i1[0] * wc1[0]), tanh_f(i1[1] * wc1[1]));
                half2v p3 = pk2(tanh_f(i1[2] * wc1[2]), tanh_f(i1[3] * wc1[3]));
                half8 t;
                t[0] = p0[0]; t[1] = p0[1]; t[2] = p1[0]; t[3] = p1[1];
                t[4] = p2[0]; t[5] = p2[1]; t[6] = p3[0]; t[7] = p3[1];
                *(half8*)&Tc[sw_off(si * CB + ciT, segT)] = t;
            }
            __syncthreads();  // drains vmcnt (async W) + lgkm (T writes)

            // --- prefetch next chunk's word values (cyclic; covered by MFMA)
            const int knext = (kk + BK) & (D - 1);
            floatx4 wn0 = *(const floatx4*)(wordRowT + knext);
            floatx4 wn1 = *(const floatx4*)(wordRowT + knext + 4);

            // --- MFMA: 2 k-steps of 32 (tail pass: only si<2)
            #pragma unroll
            for (int k2 = 0; k2 < 2; ++k2) {
                const int jb = (k2 << 2) + quad;
                half8 bf[4], af[4];
                #pragma unroll
                for (int ej = 0; ej < 4; ++ej)
                    bf[ej] = *(const half8*)&Wc[sw_off(wv * 64 + ej * 16 + l15, jb)];
                #pragma unroll
                for (int si = 0; si < 4; ++si) {
                    if (si >= 2 && !full) break;
                    af[si] = *(const half8*)&Tc[sw_off(si * CB + l15, jb)];
                }
                #pragma unroll
                for (int si = 0; si < 4; ++si) {
                    if (si >= 2 && !full) break;
                    #pragma unroll
                    for (int ej = 0; ej < 4; ++ej)
                        acc[si][ej] = __builtin_amdgcn_mfma_f32_16x16x32_f16(
                            af[si], bf[ej], acc[si][ej], 0, 0, 0);
                }
            }
            wc0 = wn0; wc1 = wn1;
        }
        // --- online softmax accumulate; acc = log2e*feat so exp2(acc) = exp(feat)
        #pragma unroll
        for (int si = 0; si < 4; ++si) {
            if (si >= slim) break;
            #pragma unroll
            for (int ej = 0; ej < 4; ++ej) {
                float ie = imgS[si][e0 + wv * 64 + ej * 16 + l15] * INVK;
                #pragma unroll
                for (int r = 0; r < 4; ++r) {
                    float ev = __builtin_amdgcn_exp2f(acc[si][ej][r]);
                    lacc[ej][r] += ev;
                    aacc[ej][r] += ie * ev;
                }
            }
        }
    }

    // --- writeout (C/D layout: col=lane&15 -> e, row=quad*4+r -> c)
    if (use_slice) {
        float* lsl = lbase + (size_t)sc * SLICE_ELEMS;
        float* asl = abase + (size_t)sc * SLICE_ELEMS;
        #pragma unroll
        for (int r = 0; r < 4; ++r) {
            int cg = c0 + quad * 4 + r;
            #pragma unroll
            for (int ej = 0; ej < 4; ++ej) {
                int eg = e0 + wv * 64 + ej * 16 + l15;
                size_t o = ((size_t)b * Cpad + cg) * D + eg;
                lsl[o] = lacc[ej][r];
                asl[o] = aacc[ej][r];
            }
        }
    } else {
        #pragma unroll
        for (int r = 0; r < 4; ++r) {
            int cg = c0 + quad * 4 + r;
            #pragma unroll
            for (int ej = 0; ej < 4; ++ej) {
                int eg = e0 + wv * 64 + ej * 16 + l15;
                atomicAdd(&lbase[((size_t)b * Cpad + cg) * D + eg], lacc[ej][r]);
                if (cg < C)
                    atomicAdd(&abase[((size_t)b * C + cg) * D + eg], aacc[ej][r]);
            }
        }
    }
}

__global__ void finalize_k(const float* __restrict__ lbase, const float* __restrict__ abase,
                           float* __restrict__ out, int use_slice) {
    int o = blockIdx.x * blockDim.x + threadIdx.x;
    if (o >= 2 * C * D) return;
    int b = o / (C * D);
    int rem = o - b * (C * D);
    int c = rem >> 9;
    int e = rem & (D - 1);
    size_t p = ((size_t)b * Cpad + c) * D + e;
    if (use_slice) {
        float l = 0.f, a = 0.f;
        #pragma unroll
        for (int scn = 0; scn < SCH; ++scn) {
            l += lbase[(size_t)scn * SLICE_ELEMS + p];
            a += abase[(size_t)scn * SLICE_ELEMS + p];
        }
        out[o] = a / l;
    } else {
        out[o] = out[o] / lbase[p];
    }
}

} // namespace

extern "C" void kernel_launch(void* const* d_in, const int* in_sizes, int n_in,
                              void* d_out, int out_size, void* d_ws, size_t ws_size,
                              hipStream_t stream) {
    const float* img  = (const float*)d_in[0];
    const float* word = (const float*)d_in[1];
    const float* fw   = (const float*)d_in[2];
    // d_in[3] = fc3_b: constant over softmax axis s -> cancels exactly.
    float* out = (float*)d_out;
    char* ws = (char*)d_ws;

    _Float16* W16sw = (_Float16*)ws;
    const int use_slice = (ws_size >= SLICE_NEED) ? 1 : 0;

    hipLaunchKernelGGL(prep_w16sw, dim3(128), dim3(256), 0, stream, fw, W16sw);

    float *lbase, *abase;
    if (use_slice) {
        lbase = (float*)(ws + LA_OFF);
        abase = (float*)(ws + LA_OFF + SL_BYTES);
    } else {
        lbase = (float*)(ws + LA_OFF);
        abase = out;
        (void)hipMemsetAsync(lbase, 0, L_BYTES, stream);
        (void)hipMemsetAsync(out, 0, (size_t)2 * C * D * 4, stream);
    }

    hipLaunchKernelGGL(semdec_mfma, dim3(64, 4, SCH), dim3(TPB), 0, stream,
                       img, word, W16sw, lbase, abase, use_slice);

    hipLaunchKernelGGL(finalize_k, dim3((2 * C * D + 255) / 256), dim3(256), 0, stream,
                       lbase, abase, out, use_slice);
}